// Round 10
// baseline (543.309 us; speedup 1.0000x reference)
//
#include <hip/hip_runtime.h>
#include <hip/hip_bf16.h>
#include <stdint.h>

#define L_DIM 384
#define MD    256      // M_DIM
#define CC    32       // C
#define ZD    128      // Z_DIM
#define NB    512      // N (batch) = K of the big GEMM
#define K2    1024     // C*C
#define MROWS 12288    // L*C

typedef __attribute__((ext_vector_type(4))) float  f32x4;
typedef __attribute__((ext_vector_type(8))) short  bf16x8;

typedef __attribute__((address_space(1))) unsigned char* gcp;
typedef __attribute__((address_space(3))) unsigned char* lcp;

#define SBAR()  __builtin_amdgcn_s_barrier()
#define LGKM0() asm volatile("s_waitcnt lgkmcnt(0)" ::: "memory")
#define VMW(n)  asm volatile("s_waitcnt vmcnt(" #n ")" ::: "memory")
#define PRIO1() __builtin_amdgcn_s_setprio(1)
#define PRIO0() __builtin_amdgcn_s_setprio(0)

__device__ __forceinline__ unsigned short f2bf(float x) {
    union { float f; unsigned u; } v; v.f = x;
    unsigned r = v.u + 0x7fffu + ((v.u >> 16) & 1u);   // round-to-nearest-even
    return (unsigned short)(r >> 16);
}

__device__ __forceinline__ uint2 pack4(unsigned short a, unsigned short b,
                                       unsigned short c, unsigned short d) {
    uint2 r; r.x = (unsigned)a | ((unsigned)b << 16);
    r.y = (unsigned)c | ((unsigned)d << 16); return r;
}

// ---------------------------------------------------------------------------
// prep: w3 -> MFMA B-fragment order w3frag[ks][zg][lane][8], k2' = b*32+a
// (b-major so op tile writes vectorize). w1/w2 -> wfrag for ln_proj.
__global__ __launch_bounds__(256) void prep_kernel(
    const float* __restrict__ w1, const float* __restrict__ w2,
    const float* __restrict__ w3,
    unsigned short* __restrict__ w3frag, unsigned short* __restrict__ wfrag)
{
    int idx = blockIdx.x * 256 + threadIdx.x;          // 147456 total
    if (idx < 131072) {
        int e = idx & 7, lane = (idx >> 3) & 63, zg = (idx >> 9) & 7, ks = idx >> 12;
        int k2p = ks * 32 + ((lane >> 4) << 3) + e;    // k2' = b*32 + a
        int wrow = (k2p & 31) * 32 + (k2p >> 5);       // = a*32 + b
        int z  = zg * 16 + (lane & 15);
        w3frag[idx] = f2bf(w3[(size_t)wrow * ZD + z]);
    } else {
        int j = idx - 131072;                           // 16384
        int e = j & 7, lane = (j >> 3) & 63, nf = (j >> 9) & 3, ks = j >> 11;
        int c = nf * 16 + (lane & 15);
        int d = ks * 32 + ((lane >> 4) << 3) + e;
        float v = (c < CC) ? w2[d * CC + c] : w1[d * CC + (c - CC)];
        wfrag[j] = f2bf(v);
    }
}

// ---------------------------------------------------------------------------
// Kernel A: LayerNorm + dual projection (a = o@w2+b2, b = o@w1+b1) via MFMA.
__global__ __launch_bounds__(256, 4) void ln_proj_kernel(
    const float* __restrict__ mm, const float* __restrict__ gamma, const float* __restrict__ beta,
    const unsigned short* __restrict__ wfrag,
    const float* __restrict__ b1, const float* __restrict__ b2,
    unsigned short* __restrict__ At, unsigned short* __restrict__ Bt)
{
    __shared__ alignas(16) char o_b[32768];            // [64 rows][512 B] swizzled

    const int tid = threadIdx.x, wv = tid >> 6, lane = tid & 63;
    const int l0 = blockIdx.y * 2;
    const int n0 = blockIdx.x * 32;

    const int l_loc = wv >> 1;
    const int nbase = (wv & 1) << 4;
    const int l_g = l0 + l_loc;
    f32x4 g4 = *(const f32x4*)(gamma + lane * 4);
    f32x4 e4 = *(const f32x4*)(beta + lane * 4);

    #pragma unroll 4
    for (int r = 0; r < 16; ++r) {
        int row_loc = wv * 16 + r;
        int n_g = n0 + nbase + r;
        const float* src = mm + ((size_t)n_g * L_DIM + l_g) * MD + lane * 4;
        f32x4 x = *(const f32x4*)src;
        float s  = x[0] + x[1] + x[2] + x[3];
        float s2 = x[0]*x[0] + x[1]*x[1] + x[2]*x[2] + x[3]*x[3];
        #pragma unroll
        for (int off = 32; off > 0; off >>= 1) {
            s  += __shfl_xor(s,  off);
            s2 += __shfl_xor(s2, off);
        }
        float mu  = s * (1.0f / MD);
        float var = s2 * (1.0f / MD) - mu * mu;
        float rs  = rsqrtf(var + 1e-5f);
        unsigned short o0 = f2bf((x[0] - mu) * rs * g4[0] + e4[0]);
        unsigned short o1 = f2bf((x[1] - mu) * rs * g4[1] + e4[1]);
        unsigned short o2 = f2bf((x[2] - mu) * rs * g4[2] + e4[2]);
        unsigned short o3 = f2bf((x[3] - mu) * rs * g4[3] + e4[3]);
        *(uint2*)(o_b + row_loc * 512 + ((lane * 8) ^ ((row_loc & 7) << 4))) = pack4(o0, o1, o2, o3);
    }
    // wave-private rows -> no barrier needed

    f32x4 acc[4] = {{0,0,0,0},{0,0,0,0},{0,0,0,0},{0,0,0,0}};
    const int lrow = lane & 15;
    const int kq16 = (lane >> 4) << 4;
    const int arow = wv * 16 + lrow;
    #pragma unroll
    for (int ks = 0; ks < 8; ++ks) {
        bf16x8 a = *(const bf16x8*)(o_b + arow * 512 + ((ks * 64 + kq16) ^ ((arow & 7) << 4)));
        #pragma unroll
        for (int nf = 0; nf < 4; ++nf) {
            bf16x8 b = *(const bf16x8*)(wfrag + (size_t)((ks * 4 + nf) * 64 + lane) * 8);
            acc[nf] = __builtin_amdgcn_mfma_f32_16x16x32_bf16(a, b, acc[nf], 0, 0, 0);
        }
    }

    const int rr0 = wv * 16 + ((lane >> 4) << 2);
    const int n_gw = n0 + (rr0 & 31);
    const int l_gw = l0 + (rr0 >> 5);
    #pragma unroll
    for (int nf = 0; nf < 4; ++nf) {
        int c = nf * 16 + lrow;
        float bias = (c < CC) ? b2[c] : b1[c - CC];
        unsigned short ob0 = f2bf(acc[nf][0] + bias);
        unsigned short ob1 = f2bf(acc[nf][1] + bias);
        unsigned short ob2 = f2bf(acc[nf][2] + bias);
        unsigned short ob3 = f2bf(acc[nf][3] + bias);
        unsigned short* dst = ((c < CC) ? At : Bt) + (size_t)(l_gw * CC + (c & 31)) * NB + n_gw;
        *(uint2*)dst = pack4(ob0, ob1, ob2, ob3);
    }
}

// ---------------------------------------------------------------------------
// Kernel B: PERSISTENT 256x256 op-tile GEMM. Grid = 256 blocks (1/CU); each
// block processes 9 tiles with a cross-tile pipeline: kt7's phases stage the
// NEXT tile's kt0 (parity-0 regions), the 2-pass epilogue lives entirely in
// parity-1 (chunked 64 KB), so the global_load_lds queue never drains between
// tiles. Uniform per-kt ledger: VMW(8) steady, VMW(0) once per tile at kt6.
__global__ __launch_bounds__(512, 2) void opm_kernel(
    const unsigned short* __restrict__ At, const unsigned short* __restrict__ Bt,
    const unsigned short* __restrict__ w3frag, const float* __restrict__ b3,
    float* __restrict__ Z)
{
    __shared__ alignas(128) char smem[131072];         // A:[2][256][64] B:[2][256][64]
    char* const Ab = smem;
    char* const Bb = smem + 65536;

    const int tid = threadIdx.x, wv = tid >> 6, lane = tid & 63;
    const int lrow = lane & 15;
    const int kq16 = (lane >> 4) << 4;
    const int lq   = lane >> 4;
    const int wr = (wv >> 2) * 128, wc = (wv & 3) * 64;

    auto stage = [&](const unsigned short* __restrict__ src, int tile0, int kt,
                     int half, int isA) {
        #pragma unroll
        for (int q = 0; q < 2; ++q) {
            int rl0 = q * 64 + wv * 8;
            int rl  = rl0 + (lane >> 3);
            int rc  = isA ? ((rl  & 63) + ((rl  >> 6) << 7) + half * 64)
                          : ((rl  & 31) + ((rl  >> 5) << 6) + half * 32);
            int rc0 = isA ? ((rl0 & 63) + ((rl0 >> 6) << 7) + half * 64)
                          : ((rl0 & 31) + ((rl0 >> 5) << 6) + half * 32);
            const unsigned short* g = src + (size_t)(tile0 + rc) * NB + kt * 64
                                      + (((lane & 7) ^ (lane >> 3)) << 3);
            char* l = (isA ? Ab : Bb) + (kt & 1) * 32768 + rc0 * 128;  // wave-uniform
            __builtin_amdgcn_global_load_lds((gcp)g, (lcp)l, 16, 0, 0);
        }
    };

    f32x4 acc[8][4];
    bf16x8 av[8], bl[4], bh[4];

    auto rdA = [&](const char* ab, int qrow) {
        #pragma unroll
        for (int mfl = 0; mfl < 4; ++mfl) {
            int row = wr + qrow * 64 + mfl * 16 + lrow;
            const char* p = ab + row * 128;
            av[mfl*2+0] = *(const bf16x8*)(p + ((     kq16) ^ ((row & 7) << 4)));
            av[mfl*2+1] = *(const bf16x8*)(p + ((64 + kq16) ^ ((row & 7) << 4)));
        }
    };
    auto rdB = [&](const char* bb, int qcol, bf16x8* bv) {
        #pragma unroll
        for (int nfl = 0; nfl < 2; ++nfl) {
            int col = wc + qcol * 32 + nfl * 16 + lrow;
            const char* p = bb + col * 128;
            bv[nfl*2+0] = *(const bf16x8*)(p + ((     kq16) ^ ((col & 7) << 4)));
            bv[nfl*2+1] = *(const bf16x8*)(p + ((64 + kq16) ^ ((col & 7) << 4)));
        }
    };
    auto MM = [&](bf16x8* bv, int mbase, int nbase) {
        #pragma unroll
        for (int mfl = 0; mfl < 4; ++mfl)
            #pragma unroll
            for (int nfl = 0; nfl < 2; ++nfl)
                #pragma unroll
                for (int ks = 0; ks < 2; ++ks)
                    acc[mbase+mfl][nbase+nfl] = __builtin_amdgcn_mfma_f32_16x16x32_bf16(
                        av[mfl*2+ks], bv[nfl*2+ks], acc[mbase+mfl][nbase+nfl], 0, 0, 0);
    };

    for (int it = 0; it < 9; ++it) {
        // XCD-aware decode (same tile set per step as the R3 dispatch slots)
        const int lin = it * 256 + blockIdx.x;
        const int xcd = lin & 7, chunk = lin >> 3;
        const int i0 = (xcd * 6 + (chunk % 6)) * 256;
        const int j0 = (chunk / 6) * 256;
        const int chn = chunk + 32;                    // next tile (it+1)
        const int ni0 = (xcd * 6 + (chn % 6)) * 256;
        const int nj0 = ((chn / 6) % 48) * 256;
        const bool hn = (it < 8);

        #pragma unroll
        for (int mf = 0; mf < 8; ++mf)
            #pragma unroll
            for (int nf = 0; nf < 4; ++nf)
                acc[mf][nf] = (f32x4){0.f, 0.f, 0.f, 0.f};

        if (it == 0) {
            stage(At, i0, 0, 0, 1); stage(Bt, j0, 0, 0, 0);
            stage(At, i0, 0, 1, 1); stage(Bt, j0, 0, 1, 0);
            VMW(0); SBAR();
        } else {
            VMW(8); SBAR();        // in-order vmcnt: proves nkt0 stages landed
        }

        // --- main loop: 8 K-tiles, uniform cadence, cross-tile staging ---
        #pragma unroll
        for (int k = 0; k < 8; ++k) {
            const char* ab = Ab + (k & 1) * 32768;
            const char* bb = Bb + (k & 1) * 32768;
            // Ph0
            rdA(ab, 0); rdB(bb, 0, bl);
            if (k == 0)              { stage(At, i0, 1, 0, 1); stage(Bt, j0, 1, 0, 0); }
            else if (k <= 5)         { stage(At, i0, k + 2, 0, 1); }
            else if (k == 7 && hn)   { stage(At, ni0, 0, 0, 1); }
            SBAR(); LGKM0(); PRIO1(); MM(bl, 0, 0); PRIO0(); SBAR();
            // Ph1
            rdB(bb, 1, bh);
            if (k == 0)              { stage(At, i0, 1, 1, 1); stage(Bt, j0, 1, 1, 0); }
            else if (k <= 5)         { stage(Bt, j0, k + 2, 0, 0); }
            else if (k == 7 && hn)   { stage(Bt, nj0, 0, 0, 0); }
            SBAR(); LGKM0(); PRIO1(); MM(bh, 0, 2); PRIO0(); SBAR();
            // Ph2
            rdA(ab, 1);
            if (k == 0)              { stage(At, i0, 2, 0, 1); stage(Bt, j0, 2, 0, 0); }
            else if (k <= 5)         { stage(At, i0, k + 2, 1, 1); }
            else if (k == 7 && hn)   { stage(At, ni0, 0, 1, 1); }
            SBAR(); LGKM0(); PRIO1(); MM(bh, 4, 2); PRIO0(); SBAR();
            // Ph3
            if (k == 0)              { stage(At, i0, 2, 1, 1); stage(Bt, j0, 2, 1, 0); }
            else if (k <= 5)         { stage(Bt, j0, k + 2, 1, 0); }
            else if (k == 7 && hn)   { stage(Bt, nj0, 0, 1, 0); }
            SBAR(); LGKM0(); PRIO1(); MM(bl, 4, 0); PRIO0();
            if (k <= 5) { VMW(8); }
            else if (k == 6) { VMW(0); }
            SBAR();
        }

        // --- 2-pass epilogue in parity-1 regions (nkt0 flies in parity-0) ---
        // op chunk addr: 32768 + (pl'>>4)*65536 + (pl'&15)*2048  (pl' in [0,32))
        const float scale = 1.0f / (float)NB;
        const int zg = wv;
        const int zc = zg * 16 + lrow;
        const float bias = b3[zc];
        const int pq = (lane >> 4) << 2;

        auto ldW = [&](int ks) -> bf16x8 {
            return *(const bf16x8*)(w3frag + (size_t)((ks * 8 + zg) * 64 + lane) * 8);
        };
        auto ldP = [&](int rg, int ks) -> bf16x8 {   // rg = chunk (0/1), slot = lrow
            int g = ks * 4 + lq;
            int b = g >> 2, jj = g & 3;
            int inner = (b * 64 + jj * 16) ^ (((b >> 1) & 7) << 4) ^ ((lrow & 7) << 4);
            return *(const bf16x8*)(smem + 32768 + rg * 65536 + lrow * 2048 + inner);
        };

        #pragma unroll
        for (int h = 0; h < 2; ++h) {
            // early-issue w3 ring (hides under op-write + barrier)
            bf16x8 wR0 = ldW(0), wR1 = ldW(1), wR2 = ldW(2), wR3 = ldW(3);

            if ((wv >> 2) == h) {                       // this wave owns rows 128h..
                #pragma unroll
                for (int mf = 0; mf < 8; ++mf) {
                    #pragma unroll
                    for (int nf = 0; nf < 4; ++nf) {
                        int col  = wc + nf * 16 + lrow;
                        int bcol = col & 31;
                        int rowl = mf * 16 + pq;        // local row in [0,128)
                        int pl   = ((rowl >> 5) << 3) | (col >> 5);   // [0,32)
                        int inner = (bcol * 64 + (rowl & 31) * 2)
                                    ^ (((bcol >> 1) & 7) << 4) ^ ((pl & 7) << 4);
                        *(uint2*)(smem + 32768 + (pl >> 4) * 65536 + (pl & 15) * 2048 + inner) =
                            pack4(f2bf(acc[mf][nf][0] * scale), f2bf(acc[mf][nf][1] * scale),
                                  f2bf(acc[mf][nf][2] * scale), f2bf(acc[mf][nf][3] * scale));
                    }
                }
            }
            LGKM0(); SBAR();

            f32x4 accP[2] = {};
            bf16x8 pA[2], pB[2];
            #pragma unroll
            for (int r = 0; r < 2; ++r) pA[r] = ldP(r, 0);
            #pragma unroll
            for (int r = 0; r < 2; ++r) pB[r] = ldP(r, 1);

            #pragma unroll
            for (int ks = 0; ks < 32; ++ks) {
                bf16x8 w = ((ks & 3) == 0) ? wR0 : ((ks & 3) == 1) ? wR1
                         : ((ks & 3) == 2) ? wR2 : wR3;
                bf16x8* pc = (ks & 1) ? pB : pA;
                PRIO1();
                accP[0] = __builtin_amdgcn_mfma_f32_16x16x32_bf16(pc[0], w, accP[0], 0, 0, 0);
                accP[1] = __builtin_amdgcn_mfma_f32_16x16x32_bf16(pc[1], w, accP[1], 0, 0, 0);
                PRIO0();
                if (ks + 4 < 32) {
                    if ((ks & 3) == 0)      wR0 = ldW(ks + 4);
                    else if ((ks & 3) == 1) wR1 = ldW(ks + 4);
                    else if ((ks & 3) == 2) wR2 = ldW(ks + 4);
                    else                    wR3 = ldW(ks + 4);
                }
                if (ks + 2 < 32) {
                    #pragma unroll
                    for (int r = 0; r < 2; ++r) pc[r] = ldP(r, ks + 2);
                }
            }

            // z-write for this half (8 stores/wave)
            #pragma unroll
            for (int pf = 0; pf < 2; ++pf) {
                #pragma unroll
                for (int rr = 0; rr < 4; ++rr) {
                    int pl = h * 32 + pf * 16 + pq + rr;
                    int ii = (i0 >> 5) + (pl >> 3);
                    int jj = (j0 >> 5) + (pl & 7);
                    Z[((size_t)ii * L_DIM + jj) * ZD + zc] = accP[pf][rr] + bias;
                }
            }
            if (h == 0) { LGKM0(); SBAR(); }           // chunk reuse by pass 2
        }
    }
}

// ---------------------------------------------------------------------------
extern "C" void kernel_launch(void* const* d_in, const int* in_sizes, int n_in,
                              void* d_out, int out_size, void* d_ws, size_t ws_size,
                              hipStream_t stream)
{
    const float* mm    = (const float*)d_in[0];
    const float* gamma = (const float*)d_in[1];
    const float* beta  = (const float*)d_in[2];
    const float* w1    = (const float*)d_in[3];
    const float* b1    = (const float*)d_in[4];
    const float* w2    = (const float*)d_in[5];
    const float* b2    = (const float*)d_in[6];
    const float* w3    = (const float*)d_in[7];
    const float* b3    = (const float*)d_in[8];

    unsigned short* At     = (unsigned short*)d_ws;                  // 12288x512
    unsigned short* Bt     = At + (size_t)MROWS * NB;                // 12288x512
    unsigned short* w3frag = Bt + (size_t)MROWS * NB;                // 131072
    unsigned short* wfrag  = w3frag + 131072;                        // 16384

    prep_kernel<<<576, 256, 0, stream>>>(w1, w2, w3, w3frag, wfrag);
    ln_proj_kernel<<<dim3(16, 192), 256, 0, stream>>>(mm, gamma, beta, wfrag, b1, b2, At, Bt);
    opm_kernel<<<256, 512, 0, stream>>>(At, Bt, w3frag, b3, (float*)d_out);
}

// Round 11
// 256.127 us; speedup vs baseline: 2.1213x; 2.1213x over previous
//
#include <hip/hip_runtime.h>
#include <hip/hip_bf16.h>
#include <stdint.h>

#define L_DIM 384
#define MD    256      // M_DIM
#define CC    32       // C
#define ZD    128      // Z_DIM
#define NB    512      // N (batch) = K of the big GEMM
#define K2    1024     // C*C
#define MROWS 12288    // L*C

typedef __attribute__((ext_vector_type(4)))  float f32x4;
typedef __attribute__((ext_vector_type(8)))  short bf16x8;

typedef __attribute__((address_space(1))) unsigned char* gcp;
typedef __attribute__((address_space(3))) unsigned char* lcp;

#define SBAR()  __builtin_amdgcn_s_barrier()
#define LGKM0() asm volatile("s_waitcnt lgkmcnt(0)" ::: "memory")
#define VMW(n)  asm volatile("s_waitcnt vmcnt(" #n ")" ::: "memory")
#define PRIO1() __builtin_amdgcn_s_setprio(1)
#define PRIO0() __builtin_amdgcn_s_setprio(0)

__device__ __forceinline__ unsigned short f2bf(float x) {
    union { float f; unsigned u; } v; v.f = x;
    unsigned r = v.u + 0x7fffu + ((v.u >> 16) & 1u);   // round-to-nearest-even
    return (unsigned short)(r >> 16);
}

__device__ __forceinline__ uint2 pack4(unsigned short a, unsigned short b,
                                       unsigned short c, unsigned short d) {
    uint2 r; r.x = (unsigned)a | ((unsigned)b << 16);
    r.y = (unsigned)c | ((unsigned)d << 16); return r;
}

// ---------------------------------------------------------------------------
// prep: w3 -> MFMA B-fragment order w3frag[ks][zg][lane][8], k2' = b*32+a
// (b-major so op tile writes vectorize). w1/w2 -> wfrag for ln_proj.
__global__ __launch_bounds__(256) void prep_kernel(
    const float* __restrict__ w1, const float* __restrict__ w2,
    const float* __restrict__ w3,
    unsigned short* __restrict__ w3frag, unsigned short* __restrict__ wfrag)
{
    int idx = blockIdx.x * 256 + threadIdx.x;          // 147456 total
    if (idx < 131072) {
        int e = idx & 7, lane = (idx >> 3) & 63, zg = (idx >> 9) & 7, ks = idx >> 12;
        int k2p = ks * 32 + ((lane >> 4) << 3) + e;    // k2' = b*32 + a
        int wrow = (k2p & 31) * 32 + (k2p >> 5);       // = a*32 + b
        int z  = zg * 16 + (lane & 15);
        w3frag[idx] = f2bf(w3[(size_t)wrow * ZD + z]);
    } else {
        int j = idx - 131072;                           // 16384
        int e = j & 7, lane = (j >> 3) & 63, nf = (j >> 9) & 3, ks = j >> 11;
        int c = nf * 16 + (lane & 15);
        int d = ks * 32 + ((lane >> 4) << 3) + e;
        float v = (c < CC) ? w2[d * CC + c] : w1[d * CC + (c - CC)];
        wfrag[j] = f2bf(v);
    }
}

// ---------------------------------------------------------------------------
// Kernel A: LayerNorm + dual projection via MFMA.
// At: row-major K-contig [ia][n] (LDS staging in opm).
// Bt: MFMA B-FRAGMENT order [frag][kc][lane][8] (direct global->reg in opm).
__global__ __launch_bounds__(256, 4) void ln_proj_kernel(
    const float* __restrict__ mm, const float* __restrict__ gamma, const float* __restrict__ beta,
    const unsigned short* __restrict__ wfrag,
    const float* __restrict__ b1, const float* __restrict__ b2,
    unsigned short* __restrict__ At, unsigned short* __restrict__ Bt)
{
    __shared__ alignas(16) char o_b[32768];            // [64 rows][512 B] swizzled

    const int tid = threadIdx.x, wv = tid >> 6, lane = tid & 63;
    const int l0 = blockIdx.y * 2;
    const int n0 = blockIdx.x * 32;

    const int l_loc = wv >> 1;
    const int nbase = (wv & 1) << 4;
    const int l_g = l0 + l_loc;
    f32x4 g4 = *(const f32x4*)(gamma + lane * 4);
    f32x4 e4 = *(const f32x4*)(beta + lane * 4);

    #pragma unroll 4
    for (int r = 0; r < 16; ++r) {
        int row_loc = wv * 16 + r;
        int n_g = n0 + nbase + r;
        const float* src = mm + ((size_t)n_g * L_DIM + l_g) * MD + lane * 4;
        f32x4 x = *(const f32x4*)src;
        float s  = x[0] + x[1] + x[2] + x[3];
        float s2 = x[0]*x[0] + x[1]*x[1] + x[2]*x[2] + x[3]*x[3];
        #pragma unroll
        for (int off = 32; off > 0; off >>= 1) {
            s  += __shfl_xor(s,  off);
            s2 += __shfl_xor(s2, off);
        }
        float mu  = s * (1.0f / MD);
        float var = s2 * (1.0f / MD) - mu * mu;
        float rs  = rsqrtf(var + 1e-5f);
        unsigned short o0 = f2bf((x[0] - mu) * rs * g4[0] + e4[0]);
        unsigned short o1 = f2bf((x[1] - mu) * rs * g4[1] + e4[1]);
        unsigned short o2 = f2bf((x[2] - mu) * rs * g4[2] + e4[2]);
        unsigned short o3 = f2bf((x[3] - mu) * rs * g4[3] + e4[3]);
        *(uint2*)(o_b + row_loc * 512 + ((lane * 8) ^ ((row_loc & 7) << 4))) = pack4(o0, o1, o2, o3);
    }
    // wave-private rows -> no barrier needed

    f32x4 acc[4] = {{0,0,0,0},{0,0,0,0},{0,0,0,0},{0,0,0,0}};
    const int lrow = lane & 15;
    const int kq16 = (lane >> 4) << 4;
    const int arow = wv * 16 + lrow;
    #pragma unroll
    for (int ks = 0; ks < 8; ++ks) {
        bf16x8 a = *(const bf16x8*)(o_b + arow * 512 + ((ks * 64 + kq16) ^ ((arow & 7) << 4)));
        #pragma unroll
        for (int nf = 0; nf < 4; ++nf) {
            bf16x8 b = *(const bf16x8*)(wfrag + (size_t)((ks * 4 + nf) * 64 + lane) * 8);
            acc[nf] = __builtin_amdgcn_mfma_f32_16x16x32_bf16(a, b, acc[nf], 0, 0, 0);
        }
    }

    const int rr0 = wv * 16 + ((lane >> 4) << 2);
    const int n_gw = n0 + (rr0 & 31);
    const int l_gw = l0 + (rr0 >> 5);
    #pragma unroll
    for (int nf = 0; nf < 4; ++nf) {
        int c = nf * 16 + lrow;
        float bias = (c < CC) ? b2[c] : b1[c - CC];
        uint2 pk = pack4(f2bf(acc[nf][0] + bias), f2bf(acc[nf][1] + bias),
                         f2bf(acc[nf][2] + bias), f2bf(acc[nf][3] + bias));
        if (c < CC) {
            // a-side: row-major K-contig
            *(uint2*)(At + (size_t)(l_gw * CC + c) * NB + n_gw) = pk;
        } else {
            // b-side: fragment order. jb = l_gw*32 + c31; frag = jb>>4.
            int c31 = c - CC;
            int f = l_gw * 2 + (c31 >> 4);
            int lanep = (c31 & 15) + (((n_gw >> 3) & 3) << 4);
            size_t addr = ((size_t)(f * 16 + (n_gw >> 5)) * 64 + lanep) * 8 + (n_gw & 7);
            *(uint2*)(Bt + addr) = pk;
        }
    }
}

// ---------------------------------------------------------------------------
// Kernel B: 256x256 op-tile GEMM. A staged in LDS (dbuf, 2-way-free swizzle);
// B fragments loaded DIRECTLY global->reg (fragment-ordered Bt), ping-pong
// unroll-2 register sets (no copies, prefetch stays in flight). 1 barrier per
// K-tile, counted VMW(8). Fused w3 epilogue (R3-verified).
__global__ __launch_bounds__(512, 2) void opm_kernel(
    const unsigned short* __restrict__ At, const unsigned short* __restrict__ Bt,
    const unsigned short* __restrict__ w3frag, const float* __restrict__ b3,
    float* __restrict__ Z)
{
    __shared__ alignas(128) char smem[131072];         // main: A dbuf 2x32KB; epi: op tile
    char* const Ab = smem;

    const int tid = threadIdx.x, wv = tid >> 6, lane = tid & 63;

    // XCD-aware remap: 2304 blocks; XCD owns 6-i-tile band x all j (j-major walk)
    const int lin = blockIdx.x;
    const int xcd = lin & 7, chunk = lin >> 3;         // chunk in [0,288)
    const int i0 = (xcd * 6 + (chunk % 6)) * 256;
    const int j0 = (chunk / 6) * 256;

    const int lrow = lane & 15;
    const int kq16 = (lane >> 4) << 4;
    const int wr = (wv >> 2) * 128, wc = (wv & 3) * 64;

    const int srow = lane >> 3;
    const int spre = ((lane & 7) ^ srow) << 3;         // pre-swizzled k (shorts)

    auto stageA = [&](int t) {
        char* base = Ab + (t & 1) * 32768;
        #pragma unroll
        for (int g = 0; g < 4; ++g) {
            int rl0 = g * 64 + wv * 8;
            const unsigned short* gp = At + (size_t)(i0 + rl0 + srow) * NB + t * 64 + spre;
            __builtin_amdgcn_global_load_lds((gcp)gp, (lcp)(base + rl0 * 128), 16, 0, 0);
        }
    };

    const int fb0 = (j0 + wc) >> 4;                    // first B frag for this wave
    auto loadB = [&](bf16x8* bv, int t) {
        #pragma unroll
        for (int nf = 0; nf < 4; ++nf)
            #pragma unroll
            for (int kk = 0; kk < 2; ++kk)
                bv[nf * 2 + kk] = *(const bf16x8*)(Bt +
                    (size_t)((fb0 + nf) * 16 + (t * 2 + kk)) * 512 + lane * 8);
    };

    f32x4 acc[8][4] = {};
    bf16x8 bA[8], bB[8], av[8];

    auto COMPUTE = [&](const char* ab, bf16x8* breg) {
        #pragma unroll
        for (int kk = 0; kk < 2; ++kk) {
            #pragma unroll
            for (int mf = 0; mf < 8; ++mf) {
                int row = wr + mf * 16 + lrow;
                av[mf] = *(const bf16x8*)(ab + row * 128 + ((kk * 64 + kq16) ^ ((row & 7) << 4)));
            }
            LGKM0();
            PRIO1();
            #pragma unroll
            for (int mf = 0; mf < 8; ++mf)
                #pragma unroll
                for (int nf = 0; nf < 4; ++nf)
                    acc[mf][nf] = __builtin_amdgcn_mfma_f32_16x16x32_bf16(
                        av[mf], breg[nf * 2 + kk], acc[mf][nf], 0, 0, 0);
            PRIO0();
        }
    };

    // prologue: stage A0, load B0, stage A1; retire A0, keep B0+A1 in flight
    stageA(0); loadB(bA, 0); stageA(1);
    VMW(12);
    SBAR();

    // main loop: unroll-2 ping-pong (bA even tiles, bB odd) — no register copies
    #pragma unroll
    for (int t = 0; t < 8; t += 2) {
        // even tile t: buf0, regs bA
        stageA(t + 1); loadB(bB, t + 1);               // t+1 <= 7
        COMPUTE(Ab, bA);
        VMW(8); SBAR();                                // retire stageA(t+1)
        // odd tile t+1: buf1, regs bB
        if (t + 1 < 7) { stageA(t + 2); loadB(bA, t + 2); }
        COMPUTE(Ab + 32768, bB);
        if (t + 1 < 7) { VMW(8); SBAR(); }
    }
    __syncthreads();   // all waves done with A-LDS before op tile reuses smem

    // ---- fused w3 epilogue (R3-verified layout) ----
    char* const opb = smem;                            // 64 pairs x 2048 B
    const int pfb = (wv >> 2) * 2, zgb = (wv & 3) * 2;
    const int row0 = pfb * 16 + lrow, row1 = row0 + 16;
    const int lq = lane >> 4;

    auto ldW = [&](int ks, int zg) -> bf16x8 {
        return *(const bf16x8*)(w3frag + (size_t)((ks * 8 + zg) * 64 + lane) * 8);
    };
    auto ldP = [&](int row, int ks) -> bf16x8 {
        int g = ks * 4 + lq;
        int b = g >> 2, jj = g & 3;
        int inner = (b * 64 + jj * 16) ^ (((b >> 1) & 7) << 4) ^ ((row & 7) << 4);
        return *(const bf16x8*)(opb + row * 2048 + inner);
    };

    // early-issue first w3 loads (hide under op-write)
    bf16x8 wA0 = ldW(0, zgb), wA1 = ldW(0, zgb + 1);
    bf16x8 wB0 = ldW(1, zgb), wB1 = ldW(1, zgb + 1);

    // write op tile (scaled, bf16), b-major k2' = b*32+a, 8B vector stores
    const float scale = 1.0f / (float)NB;
    #pragma unroll
    for (int mf = 0; mf < 8; ++mf) {
        #pragma unroll
        for (int nf = 0; nf < 4; ++nf) {
            int col = wc + nf * 16 + lrow;
            int bcol = col & 31;
            int row = wr + mf * 16 + ((lane >> 4) << 2);
            int pl = ((row >> 5) << 3) | (col >> 5);
            int a0e = row & 31;
            int inner = (bcol * 64 + a0e * 2) ^ (((bcol >> 1) & 7) << 4) ^ ((pl & 7) << 4);
            *(uint2*)(opb + pl * 2048 + inner) =
                pack4(f2bf(acc[mf][nf][0] * scale), f2bf(acc[mf][nf][1] * scale),
                      f2bf(acc[mf][nf][2] * scale), f2bf(acc[mf][nf][3] * scale));
        }
    }
    __syncthreads();

    // z-loop: 2-deep software pipeline (w3 from L2, op from LDS)
    f32x4 acc2[2][2] = {};
    bf16x8 pA0 = ldP(row0, 0), pA1 = ldP(row1, 0);
    bf16x8 pB0 = ldP(row0, 1), pB1 = ldP(row1, 1);
    for (int ks = 0; ks < 32; ks += 2) {
        bf16x8 wN0 = {}, wN1 = {}, pN0 = {}, pN1 = {};
        bf16x8 wM0 = {}, wM1 = {}, pM0 = {}, pM1 = {};
        if (ks + 2 < 32) {
            wN0 = ldW(ks + 2, zgb); wN1 = ldW(ks + 2, zgb + 1);
            pN0 = ldP(row0, ks + 2); pN1 = ldP(row1, ks + 2);
            wM0 = ldW(ks + 3, zgb); wM1 = ldW(ks + 3, zgb + 1);
            pM0 = ldP(row0, ks + 3); pM1 = ldP(row1, ks + 3);
        }
        PRIO1();
        acc2[0][0] = __builtin_amdgcn_mfma_f32_16x16x32_bf16(pA0, wA0, acc2[0][0], 0, 0, 0);
        acc2[0][1] = __builtin_amdgcn_mfma_f32_16x16x32_bf16(pA0, wA1, acc2[0][1], 0, 0, 0);
        acc2[1][0] = __builtin_amdgcn_mfma_f32_16x16x32_bf16(pA1, wA0, acc2[1][0], 0, 0, 0);
        acc2[1][1] = __builtin_amdgcn_mfma_f32_16x16x32_bf16(pA1, wA1, acc2[1][1], 0, 0, 0);
        acc2[0][0] = __builtin_amdgcn_mfma_f32_16x16x32_bf16(pB0, wB0, acc2[0][0], 0, 0, 0);
        acc2[0][1] = __builtin_amdgcn_mfma_f32_16x16x32_bf16(pB0, wB1, acc2[0][1], 0, 0, 0);
        acc2[1][0] = __builtin_amdgcn_mfma_f32_16x16x32_bf16(pB1, wB0, acc2[1][0], 0, 0, 0);
        acc2[1][1] = __builtin_amdgcn_mfma_f32_16x16x32_bf16(pB1, wB1, acc2[1][1], 0, 0, 0);
        PRIO0();
        wA0 = wN0; wA1 = wN1; pA0 = pN0; pA1 = pN1;
        wB0 = wM0; wB1 = wM1; pB0 = pM0; pB1 = pM1;
    }

    // write z
    const int pq = (lane >> 4) << 2;
    #pragma unroll
    for (int p = 0; p < 2; ++p) {
        #pragma unroll
        for (int zi = 0; zi < 2; ++zi) {
            int zc = (zgb + zi) * 16 + lrow;
            float bias = b3[zc];
            #pragma unroll
            for (int rr = 0; rr < 4; ++rr) {
                int pl = (pfb + p) * 16 + pq + rr;
                int ii = (i0 >> 5) + (pl >> 3);
                int jj = (j0 >> 5) + (pl & 7);
                Z[((size_t)ii * L_DIM + jj) * ZD + zc] = acc2[p][zi][rr] + bias;
            }
        }
    }
}

// ---------------------------------------------------------------------------
extern "C" void kernel_launch(void* const* d_in, const int* in_sizes, int n_in,
                              void* d_out, int out_size, void* d_ws, size_t ws_size,
                              hipStream_t stream)
{
    const float* mm    = (const float*)d_in[0];
    const float* gamma = (const float*)d_in[1];
    const float* beta  = (const float*)d_in[2];
    const float* w1    = (const float*)d_in[3];
    const float* b1    = (const float*)d_in[4];
    const float* w2    = (const float*)d_in[5];
    const float* b2    = (const float*)d_in[6];
    const float* w3    = (const float*)d_in[7];
    const float* b3    = (const float*)d_in[8];

    unsigned short* At     = (unsigned short*)d_ws;                  // 12288x512
    unsigned short* Bt     = At + (size_t)MROWS * NB;                // 12288x512 (frag order)
    unsigned short* w3frag = Bt + (size_t)MROWS * NB;                // 131072
    unsigned short* wfrag  = w3frag + 131072;                        // 16384

    prep_kernel<<<576, 256, 0, stream>>>(w1, w2, w3, w3frag, wfrag);
    ln_proj_kernel<<<dim3(16, 192), 256, 0, stream>>>(mm, gamma, beta, wfrag, b1, b2, At, Bt);
    opm_kernel<<<2304, 512, 0, stream>>>(At, Bt, w3frag, b3, (float*)d_out);
}

// Round 12
// 251.944 us; speedup vs baseline: 2.1565x; 1.0166x over previous
//
#include <hip/hip_runtime.h>
#include <hip/hip_bf16.h>
#include <stdint.h>

#define L_DIM 384
#define MD    256      // M_DIM
#define CC    32       // C
#define ZD    128      // Z_DIM
#define NB    512      // N (batch) = K of the big GEMM
#define K2    1024     // C*C
#define MROWS 12288    // L*C

typedef __attribute__((ext_vector_type(4)))  float f32x4;
typedef __attribute__((ext_vector_type(8)))  short bf16x8;

#define SBAR()  __builtin_amdgcn_s_barrier()
#define PRIO1() __builtin_amdgcn_s_setprio(1)
#define PRIO0() __builtin_amdgcn_s_setprio(0)

__device__ __forceinline__ unsigned short f2bf(float x) {
    union { float f; unsigned u; } v; v.f = x;
    unsigned r = v.u + 0x7fffu + ((v.u >> 16) & 1u);   // round-to-nearest-even
    return (unsigned short)(r >> 16);
}

__device__ __forceinline__ uint2 pack4(unsigned short a, unsigned short b,
                                       unsigned short c, unsigned short d) {
    uint2 r; r.x = (unsigned)a | ((unsigned)b << 16);
    r.y = (unsigned)c | ((unsigned)d << 16); return r;
}

// ---------------------------------------------------------------------------
// prep: w3 -> MFMA B-fragment order w3frag[ks][zg][lane][8], k2' = b*32+a
// (b-major so op tile writes vectorize). w1/w2 -> wfrag for ln_proj.
__global__ __launch_bounds__(256) void prep_kernel(
    const float* __restrict__ w1, const float* __restrict__ w2,
    const float* __restrict__ w3,
    unsigned short* __restrict__ w3frag, unsigned short* __restrict__ wfrag)
{
    int idx = blockIdx.x * 256 + threadIdx.x;          // 147456 total
    if (idx < 131072) {
        int e = idx & 7, lane = (idx >> 3) & 63, zg = (idx >> 9) & 7, ks = idx >> 12;
        int k2p = ks * 32 + ((lane >> 4) << 3) + e;    // k2' = b*32 + a
        int wrow = (k2p & 31) * 32 + (k2p >> 5);       // = a*32 + b
        int z  = zg * 16 + (lane & 15);
        w3frag[idx] = f2bf(w3[(size_t)wrow * ZD + z]);
    } else {
        int j = idx - 131072;                           // 16384
        int e = j & 7, lane = (j >> 3) & 63, nf = (j >> 9) & 3, ks = j >> 11;
        int c = nf * 16 + (lane & 15);
        int d = ks * 32 + ((lane >> 4) << 3) + e;
        float v = (c < CC) ? w2[d * CC + c] : w1[d * CC + (c - CC)];
        wfrag[j] = f2bf(v);
    }
}

// ---------------------------------------------------------------------------
// Kernel A: LayerNorm + dual projection via MFMA.
// BOTH At and Bt written in MFMA fragment order [frag][kc][lane][8]
// (R6-verified layout): frag = row/16, lane = (row&15) + 16*((n>>3)&3),
// elem = n&7, kc = n>>5  ->  k-within-frag = n&31.
__global__ __launch_bounds__(256, 4) void ln_proj_kernel(
    const float* __restrict__ mm, const float* __restrict__ gamma, const float* __restrict__ beta,
    const unsigned short* __restrict__ wfrag,
    const float* __restrict__ b1, const float* __restrict__ b2,
    unsigned short* __restrict__ At, unsigned short* __restrict__ Bt)
{
    __shared__ alignas(16) char o_b[32768];            // [64 rows][512 B] swizzled

    const int tid = threadIdx.x, wv = tid >> 6, lane = tid & 63;
    const int l0 = blockIdx.y * 2;
    const int n0 = blockIdx.x * 32;

    const int l_loc = wv >> 1;
    const int nbase = (wv & 1) << 4;
    const int l_g = l0 + l_loc;
    f32x4 g4 = *(const f32x4*)(gamma + lane * 4);
    f32x4 e4 = *(const f32x4*)(beta + lane * 4);

    #pragma unroll 4
    for (int r = 0; r < 16; ++r) {
        int row_loc = wv * 16 + r;
        int n_g = n0 + nbase + r;
        const float* src = mm + ((size_t)n_g * L_DIM + l_g) * MD + lane * 4;
        f32x4 x = *(const f32x4*)src;
        float s  = x[0] + x[1] + x[2] + x[3];
        float s2 = x[0]*x[0] + x[1]*x[1] + x[2]*x[2] + x[3]*x[3];
        #pragma unroll
        for (int off = 32; off > 0; off >>= 1) {
            s  += __shfl_xor(s,  off);
            s2 += __shfl_xor(s2, off);
        }
        float mu  = s * (1.0f / MD);
        float var = s2 * (1.0f / MD) - mu * mu;
        float rs  = rsqrtf(var + 1e-5f);
        unsigned short o0 = f2bf((x[0] - mu) * rs * g4[0] + e4[0]);
        unsigned short o1 = f2bf((x[1] - mu) * rs * g4[1] + e4[1]);
        unsigned short o2 = f2bf((x[2] - mu) * rs * g4[2] + e4[2]);
        unsigned short o3 = f2bf((x[3] - mu) * rs * g4[3] + e4[3]);
        *(uint2*)(o_b + row_loc * 512 + ((lane * 8) ^ ((row_loc & 7) << 4))) = pack4(o0, o1, o2, o3);
    }
    // wave-private rows -> no barrier needed

    f32x4 acc[4] = {{0,0,0,0},{0,0,0,0},{0,0,0,0},{0,0,0,0}};
    const int lrow = lane & 15;
    const int kq16 = (lane >> 4) << 4;
    const int arow = wv * 16 + lrow;
    #pragma unroll
    for (int ks = 0; ks < 8; ++ks) {
        bf16x8 a = *(const bf16x8*)(o_b + arow * 512 + ((ks * 64 + kq16) ^ ((arow & 7) << 4)));
        #pragma unroll
        for (int nf = 0; nf < 4; ++nf) {
            bf16x8 b = *(const bf16x8*)(wfrag + (size_t)((ks * 4 + nf) * 64 + lane) * 8);
            acc[nf] = __builtin_amdgcn_mfma_f32_16x16x32_bf16(a, b, acc[nf], 0, 0, 0);
        }
    }

    const int rr0 = wv * 16 + ((lane >> 4) << 2);
    const int n_gw = n0 + (rr0 & 31);
    const int l_gw = l0 + (rr0 >> 5);
    #pragma unroll
    for (int nf = 0; nf < 4; ++nf) {
        int c = nf * 16 + lrow;
        float bias = (c < CC) ? b2[c] : b1[c - CC];
        uint2 pk = pack4(f2bf(acc[nf][0] + bias), f2bf(acc[nf][1] + bias),
                         f2bf(acc[nf][2] + bias), f2bf(acc[nf][3] + bias));
        int c31 = c & 31;
        int f = l_gw * 2 + (c31 >> 4);                 // fragment index (row/16)
        int lanep = (c31 & 15) + (((n_gw >> 3) & 3) << 4);
        size_t addr = ((size_t)(f * 16 + (n_gw >> 5)) * 64 + lanep) * 8 + (n_gw & 7);
        *(uint2*)(((c < CC) ? At : Bt) + addr) = pk;
    }
}

// ---------------------------------------------------------------------------
// Kernel B: 256x256 op-tile GEMM, ZERO-SYNC main loop. Both operands loaded
// directly global->reg in fragment order (1KB coalesced per wave-load), 16
// half-K-tile steps fully unrolled, ring-2 register sets, prefetch issued
// after the consuming MFMA cluster (covered by next step's ~600-cyc cluster).
// No LDS, no barriers, no waitcnt asm in the loop: waves slip freely and the
// compiler inserts exact per-register vmcnt waits. LDS used only by the
// fused w3 epilogue (R11-verified path).
__global__ __launch_bounds__(512, 2) void opm_kernel(
    const unsigned short* __restrict__ Atf, const unsigned short* __restrict__ Btf,
    const unsigned short* __restrict__ w3frag, const float* __restrict__ b3,
    float* __restrict__ Z)
{
    __shared__ alignas(128) char smem[131072];         // epilogue op tile only

    const int tid = threadIdx.x, wv = tid >> 6, lane = tid & 63;

    // XCD-aware remap: 2304 blocks; XCD owns 6-i-tile band x all j (j-major walk)
    const int lin = blockIdx.x;
    const int xcd = lin & 7, chunk = lin >> 3;         // chunk in [0,288)
    const int i0 = (xcd * 6 + (chunk % 6)) * 256;
    const int j0 = (chunk / 6) * 256;

    const int lrow = lane & 15;
    const int wr = (wv >> 2) * 128, wc = (wv & 3) * 64;
    const int fa0 = (i0 + wr) >> 4;                    // 8 A-frags for this wave
    const int fb0 = (j0 + wc) >> 4;                    // 4 B-frags for this wave

    f32x4 acc[8][4] = {};
    bf16x8 av0[8], bv0[4], av1[8], bv1[4];

    auto loadSet = [&](bf16x8* av, bf16x8* bv, int s) {   // s = kc (half-K-tile)
        #pragma unroll
        for (int mf = 0; mf < 8; ++mf)
            av[mf] = *(const bf16x8*)(Atf + (size_t)((fa0 + mf) * 16 + s) * 512 + lane * 8);
        #pragma unroll
        for (int nf = 0; nf < 4; ++nf)
            bv[nf] = *(const bf16x8*)(Btf + (size_t)((fb0 + nf) * 16 + s) * 512 + lane * 8);
    };
    auto mmSet = [&](bf16x8* av, bf16x8* bv) {
        PRIO1();
        #pragma unroll
        for (int mf = 0; mf < 8; ++mf)
            #pragma unroll
            for (int nf = 0; nf < 4; ++nf)
                acc[mf][nf] = __builtin_amdgcn_mfma_f32_16x16x32_bf16(
                    av[mf], bv[nf], acc[mf][nf], 0, 0, 0);
        PRIO0();
    };

    // prologue: fill ring-2
    loadSet(av0, bv0, 0);
    loadSet(av1, bv1, 1);

    // 16 half-K-tile steps, fully unrolled; no synchronization of any kind
    #pragma unroll
    for (int s = 0; s < 16; ++s) {
        bf16x8* av = (s & 1) ? av1 : av0;
        bf16x8* bv = (s & 1) ? bv1 : bv0;
        mmSet(av, bv);                                  // auto-vmcnt waits set s
        if (s + 2 < 16) loadSet(av, bv, s + 2);         // refill freed set
    }

    // ---- fused w3 epilogue (R11-verified layout) ----
    char* const opb = smem;                            // 64 pairs x 2048 B
    const int pfb = (wv >> 2) * 2, zgb = (wv & 3) * 2;
    const int row0 = pfb * 16 + lrow, row1 = row0 + 16;
    const int lq = lane >> 4;

    auto ldW = [&](int ks, int zg) -> bf16x8 {
        return *(const bf16x8*)(w3frag + (size_t)((ks * 8 + zg) * 64 + lane) * 8);
    };
    auto ldP = [&](int row, int ks) -> bf16x8 {
        int g = ks * 4 + lq;
        int b = g >> 2, jj = g & 3;
        int inner = (b * 64 + jj * 16) ^ (((b >> 1) & 7) << 4) ^ ((row & 7) << 4);
        return *(const bf16x8*)(opb + row * 2048 + inner);
    };

    // early-issue first w3 loads (hide under op-write)
    bf16x8 wA0 = ldW(0, zgb), wA1 = ldW(0, zgb + 1);
    bf16x8 wB0 = ldW(1, zgb), wB1 = ldW(1, zgb + 1);

    // write op tile (scaled, bf16), b-major k2' = b*32+a, 8B vector stores
    const float scale = 1.0f / (float)NB;
    #pragma unroll
    for (int mf = 0; mf < 8; ++mf) {
        #pragma unroll
        for (int nf = 0; nf < 4; ++nf) {
            int col = wc + nf * 16 + lrow;
            int bcol = col & 31;
            int row = wr + mf * 16 + ((lane >> 4) << 2);
            int pl = ((row >> 5) << 3) | (col >> 5);
            int a0e = row & 31;
            int inner = (bcol * 64 + a0e * 2) ^ (((bcol >> 1) & 7) << 4) ^ ((pl & 7) << 4);
            *(uint2*)(opb + pl * 2048 + inner) =
                pack4(f2bf(acc[mf][nf][0] * scale), f2bf(acc[mf][nf][1] * scale),
                      f2bf(acc[mf][nf][2] * scale), f2bf(acc[mf][nf][3] * scale));
        }
    }
    __syncthreads();

    // z-loop: 2-deep software pipeline (w3 from L2, op from LDS)
    f32x4 acc2[2][2] = {};
    bf16x8 pA0 = ldP(row0, 0), pA1 = ldP(row1, 0);
    bf16x8 pB0 = ldP(row0, 1), pB1 = ldP(row1, 1);
    for (int ks = 0; ks < 32; ks += 2) {
        bf16x8 wN0 = {}, wN1 = {}, pN0 = {}, pN1 = {};
        bf16x8 wM0 = {}, wM1 = {}, pM0 = {}, pM1 = {};
        if (ks + 2 < 32) {
            wN0 = ldW(ks + 2, zgb); wN1 = ldW(ks + 2, zgb + 1);
            pN0 = ldP(row0, ks + 2); pN1 = ldP(row1, ks + 2);
            wM0 = ldW(ks + 3, zgb); wM1 = ldW(ks + 3, zgb + 1);
            pM0 = ldP(row0, ks + 3); pM1 = ldP(row1, ks + 3);
        }
        PRIO1();
        acc2[0][0] = __builtin_amdgcn_mfma_f32_16x16x32_bf16(pA0, wA0, acc2[0][0], 0, 0, 0);
        acc2[0][1] = __builtin_amdgcn_mfma_f32_16x16x32_bf16(pA0, wA1, acc2[0][1], 0, 0, 0);
        acc2[1][0] = __builtin_amdgcn_mfma_f32_16x16x32_bf16(pA1, wA0, acc2[1][0], 0, 0, 0);
        acc2[1][1] = __builtin_amdgcn_mfma_f32_16x16x32_bf16(pA1, wA1, acc2[1][1], 0, 0, 0);
        acc2[0][0] = __builtin_amdgcn_mfma_f32_16x16x32_bf16(pB0, wB0, acc2[0][0], 0, 0, 0);
        acc2[0][1] = __builtin_amdgcn_mfma_f32_16x16x32_bf16(pB0, wB1, acc2[0][1], 0, 0, 0);
        acc2[1][0] = __builtin_amdgcn_mfma_f32_16x16x32_bf16(pB1, wB0, acc2[1][0], 0, 0, 0);
        acc2[1][1] = __builtin_amdgcn_mfma_f32_16x16x32_bf16(pB1, wB1, acc2[1][1], 0, 0, 0);
        PRIO0();
        wA0 = wN0; wA1 = wN1; pA0 = pN0; pA1 = pN1;
        wB0 = wM0; wB1 = wM1; pB0 = pM0; pB1 = pM1;
    }

    // write z
    const int pq = (lane >> 4) << 2;
    #pragma unroll
    for (int p = 0; p < 2; ++p) {
        #pragma unroll
        for (int zi = 0; zi < 2; ++zi) {
            int zc = (zgb + zi) * 16 + lrow;
            float bias = b3[zc];
            #pragma unroll
            for (int rr = 0; rr < 4; ++rr) {
                int pl = (pfb + p) * 16 + pq + rr;
                int ii = (i0 >> 5) + (pl >> 3);
                int jj = (j0 >> 5) + (pl & 7);
                Z[((size_t)ii * L_DIM + jj) * ZD + zc] = acc2[p][zi][rr] + bias;
            }
        }
    }
}

// ---------------------------------------------------------------------------
extern "C" void kernel_launch(void* const* d_in, const int* in_sizes, int n_in,
                              void* d_out, int out_size, void* d_ws, size_t ws_size,
                              hipStream_t stream)
{
    const float* mm    = (const float*)d_in[0];
    const float* gamma = (const float*)d_in[1];
    const float* beta  = (const float*)d_in[2];
    const float* w1    = (const float*)d_in[3];
    const float* b1    = (const float*)d_in[4];
    const float* w2    = (const float*)d_in[5];
    const float* b2    = (const float*)d_in[6];
    const float* w3    = (const float*)d_in[7];
    const float* b3    = (const float*)d_in[8];

    unsigned short* At     = (unsigned short*)d_ws;                  // frag order
    unsigned short* Bt     = At + (size_t)MROWS * NB;                // frag order
    unsigned short* w3frag = Bt + (size_t)MROWS * NB;                // 131072
    unsigned short* wfrag  = w3frag + 131072;                        // 16384

    prep_kernel<<<576, 256, 0, stream>>>(w1, w2, w3, w3frag, wfrag);
    ln_proj_kernel<<<dim3(16, 192), 256, 0, stream>>>(mm, gamma, beta, wfrag, b1, b2, At, Bt);
    opm_kernel<<<2304, 512, 0, stream>>>(At, Bt, w3frag, b3, (float*)d_out);
}